// Round 2
// baseline (943.197 us; speedup 1.0000x reference)
//
#include <hip/hip_runtime.h>

#define NN 50000
#define NE 800000

typedef __attribute__((ext_vector_type(8))) short bf16x8;
typedef __attribute__((ext_vector_type(4))) float f32x4;

__device__ __forceinline__ short f2bf(float f) {
    union { float f; unsigned u; } v; v.f = f;
    return (short)((v.u + 0x7fffu + ((v.u >> 16) & 1u)) >> 16);
}

__device__ __forceinline__ bf16x8 cvt8(const float* __restrict__ p) {
    const f32x4 a = *(const f32x4*)p;
    const f32x4 b = *(const f32x4*)(p + 4);
    bf16x8 r;
#pragma unroll
    for (int j = 0; j < 4; ++j) { r[j] = f2bf(a[j]); r[j + 4] = f2bf(b[j]); }
    return r;
}

// Stage W (KROWS x 128 row-major fp32) into LDS as swizzled bf16 MFMA B-fragments.
template<int KROWS, int NTHREADS>
__device__ __forceinline__ void stage_w(const float* __restrict__ W, short* lds, int tid) {
    constexpr int NSLOT = (KROWS / 32) * 8 * 64;
#pragma unroll 1
    for (int slot = tid; slot < NSLOT; slot += NTHREADS) {
        const int f = slot >> 6, l = slot & 63;
        const int s = f >> 3, t = f & 7;
        const int k0 = 32 * s + ((l >> 4) << 3);
        const int n = 16 * t + (l & 15);
        bf16x8 v;
#pragma unroll
        for (int j = 0; j < 8; ++j) v[j] = f2bf(W[(k0 + j) * 128 + n]);
        *(bf16x8*)(lds + slot * 8) = v;
    }
}

// ---------------- counting sort by dst ----------------

__global__ void hist_kernel(const int* __restrict__ eidx, int* __restrict__ cnt) {
    const int e = blockIdx.x * blockDim.x + threadIdx.x;
    if (e < NE) atomicAdd(&cnt[eidx[NE + e]], 1);
}

__global__ __launch_bounds__(1024) void scan1_kernel(const int* __restrict__ cnt,
                                                     int* __restrict__ part,
                                                     int* __restrict__ bsum) {
    __shared__ int s[1024];
    const int t = threadIdx.x;
    const int i = blockIdx.x * 1024 + t;
    const int v = (i < NN) ? cnt[i] : 0;
    int x = v;
    s[t] = x;
    __syncthreads();
    for (int off = 1; off < 1024; off <<= 1) {
        const int y = (t >= off) ? s[t - off] : 0;
        __syncthreads();
        x += y;
        s[t] = x;
        __syncthreads();
    }
    if (i < NN) part[i] = x - v;  // exclusive within block
    if (t == 1023) bsum[blockIdx.x] = x;
}

__global__ void scan2_kernel(const int* __restrict__ bsum, int* __restrict__ boff, int nb) {
    if (threadIdx.x == 0 && blockIdx.x == 0) {
        int acc = 0;
        for (int b = 0; b < nb; ++b) { boff[b] = acc; acc += bsum[b]; }
    }
}

__global__ __launch_bounds__(1024) void scan3_kernel(const int* __restrict__ part,
                                                     const int* __restrict__ boff,
                                                     int* __restrict__ rowptr,
                                                     int* __restrict__ cursor) {
    const int i = blockIdx.x * 1024 + threadIdx.x;
    if (i < NN) {
        const int v = part[i] + boff[i >> 10];
        rowptr[i] = v;
        cursor[i] = v;
    }
    if (i == 0) rowptr[NN] = NE;
}

__global__ void scatter_kernel(const int* __restrict__ eidx, int* __restrict__ cursor,
                               int* __restrict__ perm) {
    const int e = blockIdx.x * blockDim.x + threadIdx.x;
    if (e < NE) {
        const int d = eidx[NE + e];
        const int pos = atomicAdd(&cursor[d], 1);
        perm[pos] = e;
    }
}

// ---------------- P = h @ Wm1[0:128], Q = h @ Wm1[128:256] ----------------

__global__ __launch_bounds__(256) void node_pq_kernel(
    const float* __restrict__ h, const float* __restrict__ Wm1,
    float* __restrict__ P, float* __restrict__ Q)
{
    __shared__ short sWa[16384];
    __shared__ short sWb[16384];
    const int tid = threadIdx.x;
    stage_w<128, 256>(Wm1, sWa, tid);
    stage_w<128, 256>(Wm1 + 128 * 128, sWb, tid);
    __syncthreads();
    const int wave = tid >> 6, lane = tid & 63;
    const int q = lane >> 4, col = lane & 15;
    for (int tile = blockIdx.x * 4 + wave; tile < NN / 16; tile += gridDim.x * 4) {
        const int r0 = tile * 16;
        f32x4 aP[8], aQ[8];
#pragma unroll
        for (int t = 0; t < 8; ++t) { aP[t] = {0.f, 0.f, 0.f, 0.f}; aQ[t] = {0.f, 0.f, 0.f, 0.f}; }
#pragma unroll
        for (int s = 0; s < 4; ++s) {
            const bf16x8 ah = cvt8(&h[(r0 + col) * 128 + s * 32 + q * 8]);
#pragma unroll
            for (int t = 0; t < 8; ++t) {
                const bf16x8 ba = *(const bf16x8*)(sWa + ((s * 8 + t) * 64 + lane) * 8);
                const bf16x8 bb = *(const bf16x8*)(sWb + ((s * 8 + t) * 64 + lane) * 8);
                aP[t] = __builtin_amdgcn_mfma_f32_16x16x32_bf16(ah, ba, aP[t], 0, 0, 0);
                aQ[t] = __builtin_amdgcn_mfma_f32_16x16x32_bf16(ah, bb, aQ[t], 0, 0, 0);
            }
        }
#pragma unroll
        for (int t = 0; t < 8; ++t)
#pragma unroll
            for (int r = 0; r < 4; ++r) {
                const int o = (r0 + q * 4 + r) * 128 + t * 16 + col;
                P[o] = aP[t][r];
                Q[o] = aQ[t][r];
            }
    }
}

// ---------------- per-node CSR aggregation (no atomics) ----------------
// wave owns node n: for each 16-edge chunk of its dst-sorted run,
// msg = relu(relu(P[src]+Q[n]+b1 + ea@W1c) @ Wm2 + b2); masked row-reduce; write agg[n].
__global__ __launch_bounds__(512) void agg_kernel(
    const float* __restrict__ P, const float* __restrict__ Q,
    const float* __restrict__ ea, const float* __restrict__ W1c,
    const float* __restrict__ bm1, const float* __restrict__ Wm2,
    const float* __restrict__ bm2, const int* __restrict__ eidx,
    const int* __restrict__ rowptr, const int* __restrict__ perm,
    float* __restrict__ agg)
{
    __shared__ short sW2[16384];
    __shared__ short sW1c[4096];
    __shared__ float sb1[128];
    __shared__ float sb2[128];
    __shared__ short sX[8][16 * 136];
    const int tid = threadIdx.x;
    stage_w<128, 512>(Wm2, sW2, tid);
    stage_w<32, 512>(W1c, sW1c, tid);
    if (tid < 128) { sb1[tid] = bm1[tid]; sb2[tid] = bm2[tid]; }
    __syncthreads();
    const int wave = tid >> 6, lane = tid & 63;
    const int q = lane >> 4, col = lane & 15;
    short* myX = &sX[wave][0];
    const int gw = gridDim.x * 8;
    for (int n = blockIdx.x * 8 + wave; n < NN; n += gw) {
        const int base = rowptr[n];
        const int end = rowptr[n + 1];
        float qrow[8], accA[8];
#pragma unroll
        for (int t = 0; t < 8; ++t) {
            qrow[t] = Q[n * 128 + t * 16 + col] + sb1[t * 16 + col];
            accA[t] = 0.f;
        }
        for (int c = base; c < end; c += 16) {
            // edge ids for A rows (m = col) and C rows (q*4+r)
            const int pA = (c + col < end) ? perm[c + col] : 0;
            int srR[4], valid[4];
#pragma unroll
            for (int r = 0; r < 4; ++r) {
                const int idx = c + q * 4 + r;
                valid[r] = idx < end;
                srR[r] = valid[r] ? eidx[perm[idx]] : 0;
            }
            // layer-1 acc: P[src] + Q[n] + b1 (C-layout)
            f32x4 acc1[8];
#pragma unroll
            for (int t = 0; t < 8; ++t)
#pragma unroll
                for (int r = 0; r < 4; ++r)
                    acc1[t][r] = P[srR[r] * 128 + t * 16 + col] + qrow[t];
            // + ea @ W1c
            const bf16x8 aea = cvt8(&ea[pA * 32 + q * 8]);
#pragma unroll
            for (int t = 0; t < 8; ++t) {
                const bf16x8 bw = *(const bf16x8*)(sW1c + (t * 64 + lane) * 8);
                acc1[t] = __builtin_amdgcn_mfma_f32_16x16x32_bf16(aea, bw, acc1[t], 0, 0, 0);
            }
            // relu -> bf16 -> LDS
#pragma unroll
            for (int t = 0; t < 8; ++t)
#pragma unroll
                for (int r = 0; r < 4; ++r) {
                    const float x = acc1[t][r];
                    myX[(q * 4 + r) * 136 + t * 16 + col] = f2bf(x > 0.f ? x : 0.f);
                }
            // layer 2
            f32x4 acc2[8];
#pragma unroll
            for (int t = 0; t < 8; ++t) {
                const float b = sb2[t * 16 + col];
                acc2[t] = {b, b, b, b};
            }
#pragma unroll
            for (int s = 0; s < 4; ++s) {
                const bf16x8 ax = *(const bf16x8*)(myX + col * 136 + s * 32 + q * 8);
#pragma unroll
                for (int t = 0; t < 8; ++t) {
                    const bf16x8 bw = *(const bf16x8*)(sW2 + ((s * 8 + t) * 64 + lane) * 8);
                    acc2[t] = __builtin_amdgcn_mfma_f32_16x16x32_bf16(ax, bw, acc2[t], 0, 0, 0);
                }
            }
            // masked relu row-reduce: per-lane over r, butterfly over q
#pragma unroll
            for (int t = 0; t < 8; ++t) {
                float s = 0.f;
#pragma unroll
                for (int r = 0; r < 4; ++r) {
                    const float m = acc2[t][r];
                    s += (valid[r] && m > 0.f) ? m : 0.f;
                }
                s += __shfl_xor(s, 16);
                s += __shfl_xor(s, 32);
                accA[t] += s;
            }
        }
        if (q == 0) {
#pragma unroll
            for (int t = 0; t < 8; ++t) agg[n * 128 + t * 16 + col] = accA[t];
        }
    }
}

// ---------------- update MLP + residual ----------------

__global__ __launch_bounds__(512) void update_kernel(
    const float* __restrict__ h, const float* __restrict__ agg,
    const float* __restrict__ Wu1, const float* __restrict__ bu1,
    const float* __restrict__ Wu2, const float* __restrict__ bu2,
    float* __restrict__ out)
{
    __shared__ short sWa[16384];
    __shared__ short sWb[16384];
    __shared__ short sW2[16384];
    __shared__ float sb1[128];
    __shared__ float sb2[128];
    __shared__ short sX[8][16 * 136];
    const int tid = threadIdx.x;
    stage_w<128, 512>(Wu1, sWa, tid);
    stage_w<128, 512>(Wu1 + 128 * 128, sWb, tid);
    stage_w<128, 512>(Wu2, sW2, tid);
    if (tid < 128) { sb1[tid] = bu1[tid]; sb2[tid] = bu2[tid]; }
    __syncthreads();
    const int wave = tid >> 6, lane = tid & 63;
    const int q = lane >> 4, col = lane & 15;
    short* myX = &sX[wave][0];
    for (int tile = blockIdx.x * 8 + wave; tile < NN / 16; tile += gridDim.x * 8) {
        const int r0 = tile * 16;
        f32x4 acc1[8];
#pragma unroll
        for (int t = 0; t < 8; ++t) {
            const float b = sb1[t * 16 + col];
            acc1[t] = {b, b, b, b};
        }
#pragma unroll
        for (int s = 0; s < 4; ++s) {
            const bf16x8 ahh = cvt8(&h[(r0 + col) * 128 + s * 32 + q * 8]);
            const bf16x8 aag = cvt8(&agg[(r0 + col) * 128 + s * 32 + q * 8]);
#pragma unroll
            for (int t = 0; t < 8; ++t) {
                const bf16x8 ba = *(const bf16x8*)(sWa + ((s * 8 + t) * 64 + lane) * 8);
                const bf16x8 bb = *(const bf16x8*)(sWb + ((s * 8 + t) * 64 + lane) * 8);
                acc1[t] = __builtin_amdgcn_mfma_f32_16x16x32_bf16(ahh, ba, acc1[t], 0, 0, 0);
                acc1[t] = __builtin_amdgcn_mfma_f32_16x16x32_bf16(aag, bb, acc1[t], 0, 0, 0);
            }
        }
#pragma unroll
        for (int t = 0; t < 8; ++t)
#pragma unroll
            for (int r = 0; r < 4; ++r) {
                const float x = acc1[t][r];
                myX[(q * 4 + r) * 136 + t * 16 + col] = f2bf(x > 0.f ? x : 0.f);
            }
        f32x4 acc2[8];
#pragma unroll
        for (int t = 0; t < 8; ++t) {
            const float b = sb2[t * 16 + col];
#pragma unroll
            for (int r = 0; r < 4; ++r)
                acc2[t][r] = b + h[(r0 + q * 4 + r) * 128 + t * 16 + col];
        }
#pragma unroll
        for (int s = 0; s < 4; ++s) {
            const bf16x8 ax = *(const bf16x8*)(myX + col * 136 + s * 32 + q * 8);
#pragma unroll
            for (int t = 0; t < 8; ++t) {
                const bf16x8 bw = *(const bf16x8*)(sW2 + ((s * 8 + t) * 64 + lane) * 8);
                acc2[t] = __builtin_amdgcn_mfma_f32_16x16x32_bf16(ax, bw, acc2[t], 0, 0, 0);
            }
        }
#pragma unroll
        for (int t = 0; t < 8; ++t)
#pragma unroll
            for (int r = 0; r < 4; ++r)
                out[(r0 + q * 4 + r) * 128 + t * 16 + col] = acc2[t][r];
    }
}

extern "C" void kernel_launch(void* const* d_in, const int* in_sizes, int n_in,
                              void* d_out, int out_size, void* d_ws, size_t ws_size,
                              hipStream_t stream) {
    const float* h   = (const float*)d_in[0];
    const float* ea  = (const float*)d_in[1];
    const float* Wm1 = (const float*)d_in[2];
    const float* bm1 = (const float*)d_in[3];
    const float* Wm2 = (const float*)d_in[4];
    const float* bm2 = (const float*)d_in[5];
    const float* Wu1 = (const float*)d_in[6];
    const float* bu1 = (const float*)d_in[7];
    const float* Wu2 = (const float*)d_in[8];
    const float* bu2 = (const float*)d_in[9];
    const int* eidx  = (const int*)d_in[10];
    float* out = (float*)d_out;

    float* P   = (float*)d_ws;           // NN*128
    float* Q   = P + (size_t)NN * 128;   // NN*128
    float* agg = Q + (size_t)NN * 128;   // NN*128
    int* cnt    = (int*)(agg + (size_t)NN * 128);  // NN
    int* part   = cnt + NN;                        // NN
    int* bsum   = part + NN;                       // 64
    int* boff   = bsum + 64;                       // 64
    int* rowptr = boff + 64;                       // NN+1
    int* cursor = rowptr + NN + 1;                 // NN
    int* perm   = cursor + NN + 3;                 // NE (16B-ish aligned)

    const int NB_SCAN = (NN + 1023) / 1024;  // 49
    const int NB_E = (NE + 255) / 256;       // 3125

    hipMemsetAsync(cnt, 0, (size_t)NN * sizeof(int), stream);
    node_pq_kernel<<<512, 256, 0, stream>>>(h, Wm1, P, Q);
    hist_kernel<<<NB_E, 256, 0, stream>>>(eidx, cnt);
    scan1_kernel<<<NB_SCAN, 1024, 0, stream>>>(cnt, part, bsum);
    scan2_kernel<<<1, 64, 0, stream>>>(bsum, boff, NB_SCAN);
    scan3_kernel<<<NB_SCAN, 1024, 0, stream>>>(part, boff, rowptr, cursor);
    scatter_kernel<<<NB_E, 256, 0, stream>>>(eidx, cursor, perm);
    agg_kernel<<<512, 512, 0, stream>>>(P, Q, ea, Wm1 + 256 * 128, bm1, Wm2, bm2,
                                        eidx, rowptr, perm, agg);
    update_kernel<<<256, 512, 0, stream>>>(h, agg, Wu1, bu1, Wu2, bu2, out);
}

// Round 3
// 688.890 us; speedup vs baseline: 1.3692x; 1.3692x over previous
//
#include <hip/hip_runtime.h>

#define NN 50000
#define NE 800000

typedef __attribute__((ext_vector_type(8))) short bf16x8;
typedef __attribute__((ext_vector_type(4))) float f32x4;

__device__ __forceinline__ short f2bf(float f) {
    union { float f; unsigned u; } v; v.f = f;
    return (short)((v.u + 0x7fffu + ((v.u >> 16) & 1u)) >> 16);
}

__device__ __forceinline__ float bf2f(short s) {
    union { unsigned u; float f; } v;
    v.u = ((unsigned)(unsigned short)s) << 16;
    return v.f;
}

__device__ __forceinline__ bf16x8 cvt8(const float* __restrict__ p) {
    const f32x4 a = *(const f32x4*)p;
    const f32x4 b = *(const f32x4*)(p + 4);
    bf16x8 r;
#pragma unroll
    for (int j = 0; j < 4; ++j) { r[j] = f2bf(a[j]); r[j + 4] = f2bf(b[j]); }
    return r;
}

// Stage W (KROWS x 128 row-major fp32) into LDS as swizzled bf16 MFMA B-fragments.
// If SIGMA: permute input rows k -> sigma(k) = (k&7)*16 + (k>>3), matching the
// X-tilde column swizzle (C-layout t*16+col packed as col*8+t). Only valid KROWS=128.
template<int KROWS, int NTHREADS, bool SIGMA>
__device__ __forceinline__ void stage_w(const float* __restrict__ W, short* lds, int tid) {
    constexpr int NSLOT = (KROWS / 32) * 8 * 64;
#pragma unroll 1
    for (int slot = tid; slot < NSLOT; slot += NTHREADS) {
        const int f = slot >> 6, l = slot & 63;
        const int s = f >> 3, t = f & 7;
        const int k0 = 32 * s + ((l >> 4) << 3);
        const int n = 16 * t + (l & 15);
        bf16x8 v;
#pragma unroll
        for (int j = 0; j < 8; ++j) {
            int k = k0 + j;
            if (SIGMA) k = (k & 7) * 16 + (k >> 3);
            v[j] = f2bf(W[k * 128 + n]);
        }
        *(bf16x8*)(lds + slot * 8) = v;
    }
}

// P~ = sigma-swizzled bf16 of h @ Wm1[0:128], Q~ same for Wm1[128:256].
// Element (node, t*16+col) stored at node*128 + col*8 + t.
__global__ __launch_bounds__(256) void node_pq_kernel(
    const float* __restrict__ h, const float* __restrict__ Wm1,
    short* __restrict__ Pb, short* __restrict__ Qb)
{
    __shared__ short sWa[16384];
    __shared__ short sWb[16384];
    const int tid = threadIdx.x;
    stage_w<128, 256, false>(Wm1, sWa, tid);
    stage_w<128, 256, false>(Wm1 + 128 * 128, sWb, tid);
    __syncthreads();
    const int wave = tid >> 6, lane = tid & 63;
    const int q = lane >> 4, col = lane & 15;
    for (int tile = blockIdx.x * 4 + wave; tile < NN / 16; tile += gridDim.x * 4) {
        const int r0 = tile * 16;
        f32x4 aP[8], aQ[8];
#pragma unroll
        for (int t = 0; t < 8; ++t) { aP[t] = {0.f, 0.f, 0.f, 0.f}; aQ[t] = {0.f, 0.f, 0.f, 0.f}; }
#pragma unroll
        for (int s = 0; s < 4; ++s) {
            const bf16x8 ah = cvt8(&h[(r0 + col) * 128 + s * 32 + q * 8]);
#pragma unroll
            for (int t = 0; t < 8; ++t) {
                const bf16x8 ba = *(const bf16x8*)(sWa + ((s * 8 + t) * 64 + lane) * 8);
                const bf16x8 bb = *(const bf16x8*)(sWb + ((s * 8 + t) * 64 + lane) * 8);
                aP[t] = __builtin_amdgcn_mfma_f32_16x16x32_bf16(ah, ba, aP[t], 0, 0, 0);
                aQ[t] = __builtin_amdgcn_mfma_f32_16x16x32_bf16(ah, bb, aQ[t], 0, 0, 0);
            }
        }
#pragma unroll
        for (int r = 0; r < 4; ++r) {
            const size_t row = (size_t)(r0 + q * 4 + r) * 128;
            bf16x8 vp, vq;
#pragma unroll
            for (int t = 0; t < 8; ++t) { vp[t] = f2bf(aP[t][r]); vq[t] = f2bf(aQ[t][r]); }
            *(bf16x8*)(Pb + row + col * 8) = vp;
            *(bf16x8*)(Qb + row + col * 8) = vq;
        }
    }
}

// Per 16-edge tile: acc1 = P~[src] + Q~[dst] + b1 + ea@W1c; X = relu(acc1);
// msg = relu(X @ Wm2 + b2); atomic scatter-add to agg.
__global__ __launch_bounds__(512) void edge_kernel(
    const short* __restrict__ Pb, const short* __restrict__ Qb,
    const float* __restrict__ ea, const float* __restrict__ W1c,
    const float* __restrict__ bm1, const float* __restrict__ Wm2,
    const float* __restrict__ bm2, const int* __restrict__ eidx,
    float* __restrict__ agg)
{
    __shared__ short sW2[16384];   // Wm2, sigma-permuted rows
    __shared__ short sW1c[4096];
    __shared__ short sX[8][16 * 136];  // X-tilde, per-wave
    const int tid = threadIdx.x;
    const int wave = tid >> 6, lane = tid & 63;
    const int q = lane >> 4, col = lane & 15;
    float b1v[8], b2v[8];
#pragma unroll
    for (int t = 0; t < 8; ++t) { b1v[t] = bm1[t * 16 + col]; b2v[t] = bm2[t * 16 + col]; }
    stage_w<128, 512, true>(Wm2, sW2, tid);
    stage_w<32, 512, false>(W1c, sW1c, tid);
    __syncthreads();
    short* myX = &sX[wave][0];
    for (int tile = blockIdx.x * 8 + wave; tile < NE / 16; tile += gridDim.x * 8) {
        const int e0 = tile * 16;
        int sr[4], dr[4];
#pragma unroll
        for (int r = 0; r < 4; ++r) {
            const int e = e0 + q * 4 + r;
            sr[r] = eidx[e];
            dr[r] = eidx[NE + e];
        }
        // layer-1 acc: one 16B vector gather per (array, r)
        f32x4 acc1[8];
#pragma unroll
        for (int r = 0; r < 4; ++r) {
            const bf16x8 vp = *(const bf16x8*)(Pb + (size_t)sr[r] * 128 + col * 8);
            const bf16x8 vq = *(const bf16x8*)(Qb + (size_t)dr[r] * 128 + col * 8);
#pragma unroll
            for (int t = 0; t < 8; ++t)
                acc1[t][r] = bf2f(vp[t]) + bf2f(vq[t]) + b1v[t];
        }
        // + ea @ W1c
        const bf16x8 aea = cvt8(&ea[(e0 + col) * 32 + q * 8]);
#pragma unroll
        for (int t = 0; t < 8; ++t) {
            const bf16x8 bw = *(const bf16x8*)(sW1c + (t * 64 + lane) * 8);
            acc1[t] = __builtin_amdgcn_mfma_f32_16x16x32_bf16(aea, bw, acc1[t], 0, 0, 0);
        }
        // relu -> bf16 -> X-tilde LDS (vector b128 writes)
#pragma unroll
        for (int r = 0; r < 4; ++r) {
            bf16x8 vx;
#pragma unroll
            for (int t = 0; t < 8; ++t) {
                const float x = acc1[t][r];
                vx[t] = f2bf(x > 0.f ? x : 0.f);
            }
            *(bf16x8*)(myX + (q * 4 + r) * 136 + col * 8) = vx;
        }
        // layer 2: msg = relu(X~ @ W2~ + b2)
        f32x4 acc2[8];
#pragma unroll
        for (int t = 0; t < 8; ++t) {
            const float b = b2v[t];
            acc2[t] = {b, b, b, b};
        }
#pragma unroll
        for (int s = 0; s < 4; ++s) {
            const bf16x8 ax = *(const bf16x8*)(myX + col * 136 + s * 32 + q * 8);
#pragma unroll
            for (int t = 0; t < 8; ++t) {
                const bf16x8 bw = *(const bf16x8*)(sW2 + ((s * 8 + t) * 64 + lane) * 8);
                acc2[t] = __builtin_amdgcn_mfma_f32_16x16x32_bf16(ax, bw, acc2[t], 0, 0, 0);
            }
        }
        // relu + scatter-add (skip non-positive)
#pragma unroll
        for (int t = 0; t < 8; ++t)
#pragma unroll
            for (int r = 0; r < 4; ++r) {
                const float m = acc2[t][r];
                if (m > 0.f)
                    unsafeAtomicAdd(&agg[(size_t)dr[r] * 128 + t * 16 + col], m);
            }
    }
}

// h_new = h + Wu2^T relu(Wu1^T concat(h,agg) + bu1) + bu2
__global__ __launch_bounds__(512) void update_kernel(
    const float* __restrict__ h, const float* __restrict__ agg,
    const float* __restrict__ Wu1, const float* __restrict__ bu1,
    const float* __restrict__ Wu2, const float* __restrict__ bu2,
    float* __restrict__ out)
{
    __shared__ short sWa[16384];
    __shared__ short sWb[16384];
    __shared__ short sW2[16384];   // Wu2, sigma-permuted rows
    __shared__ short sX[8][16 * 136];
    const int tid = threadIdx.x;
    const int wave = tid >> 6, lane = tid & 63;
    const int q = lane >> 4, col = lane & 15;
    float b1v[8], b2v[8];
#pragma unroll
    for (int t = 0; t < 8; ++t) { b1v[t] = bu1[t * 16 + col]; b2v[t] = bu2[t * 16 + col]; }
    stage_w<128, 512, false>(Wu1, sWa, tid);
    stage_w<128, 512, false>(Wu1 + 128 * 128, sWb, tid);
    stage_w<128, 512, true>(Wu2, sW2, tid);
    __syncthreads();
    short* myX = &sX[wave][0];
    for (int tile = blockIdx.x * 8 + wave; tile < NN / 16; tile += gridDim.x * 8) {
        const int r0 = tile * 16;
        f32x4 acc1[8];
#pragma unroll
        for (int t = 0; t < 8; ++t) {
            const float b = b1v[t];
            acc1[t] = {b, b, b, b};
        }
#pragma unroll
        for (int s = 0; s < 4; ++s) {
            const bf16x8 ahh = cvt8(&h[(r0 + col) * 128 + s * 32 + q * 8]);
            const bf16x8 aag = cvt8(&agg[(r0 + col) * 128 + s * 32 + q * 8]);
#pragma unroll
            for (int t = 0; t < 8; ++t) {
                const bf16x8 ba = *(const bf16x8*)(sWa + ((s * 8 + t) * 64 + lane) * 8);
                const bf16x8 bb = *(const bf16x8*)(sWb + ((s * 8 + t) * 64 + lane) * 8);
                acc1[t] = __builtin_amdgcn_mfma_f32_16x16x32_bf16(ahh, ba, acc1[t], 0, 0, 0);
                acc1[t] = __builtin_amdgcn_mfma_f32_16x16x32_bf16(aag, bb, acc1[t], 0, 0, 0);
            }
        }
#pragma unroll
        for (int r = 0; r < 4; ++r) {
            bf16x8 vx;
#pragma unroll
            for (int t = 0; t < 8; ++t) {
                const float x = acc1[t][r];
                vx[t] = f2bf(x > 0.f ? x : 0.f);
            }
            *(bf16x8*)(myX + (q * 4 + r) * 136 + col * 8) = vx;
        }
        f32x4 acc2[8];
#pragma unroll
        for (int t = 0; t < 8; ++t) {
            const float b = b2v[t];
#pragma unroll
            for (int r = 0; r < 4; ++r)
                acc2[t][r] = b + h[(r0 + q * 4 + r) * 128 + t * 16 + col];
        }
#pragma unroll
        for (int s = 0; s < 4; ++s) {
            const bf16x8 ax = *(const bf16x8*)(myX + col * 136 + s * 32 + q * 8);
#pragma unroll
            for (int t = 0; t < 8; ++t) {
                const bf16x8 bw = *(const bf16x8*)(sW2 + ((s * 8 + t) * 64 + lane) * 8);
                acc2[t] = __builtin_amdgcn_mfma_f32_16x16x32_bf16(ax, bw, acc2[t], 0, 0, 0);
            }
        }
#pragma unroll
        for (int t = 0; t < 8; ++t)
#pragma unroll
            for (int r = 0; r < 4; ++r)
                out[(r0 + q * 4 + r) * 128 + t * 16 + col] = acc2[t][r];
    }
}

extern "C" void kernel_launch(void* const* d_in, const int* in_sizes, int n_in,
                              void* d_out, int out_size, void* d_ws, size_t ws_size,
                              hipStream_t stream) {
    const float* h   = (const float*)d_in[0];
    const float* ea  = (const float*)d_in[1];
    const float* Wm1 = (const float*)d_in[2];
    const float* bm1 = (const float*)d_in[3];
    const float* Wm2 = (const float*)d_in[4];
    const float* bm2 = (const float*)d_in[5];
    const float* Wu1 = (const float*)d_in[6];
    const float* bu1 = (const float*)d_in[7];
    const float* Wu2 = (const float*)d_in[8];
    const float* bu2 = (const float*)d_in[9];
    const int* eidx  = (const int*)d_in[10];
    float* out = (float*)d_out;

    short* Pb  = (short*)d_ws;                       // NN*128 bf16
    short* Qb  = Pb + (size_t)NN * 128;              // NN*128 bf16
    float* agg = (float*)(Qb + (size_t)NN * 128);    // NN*128 fp32

    hipMemsetAsync(agg, 0, (size_t)NN * 128 * sizeof(float), stream);
    node_pq_kernel<<<512, 256, 0, stream>>>(h, Wm1, Pb, Qb);
    edge_kernel<<<512, 512, 0, stream>>>(Pb, Qb, ea, Wm1 + 256 * 128, bm1, Wm2, bm2, eidx, agg);
    update_kernel<<<256, 512, 0, stream>>>(h, agg, Wu1, bu1, Wu2, bu2, out);
}

// Round 4
// 650.047 us; speedup vs baseline: 1.4510x; 1.0598x over previous
//
#include <hip/hip_runtime.h>

#define NN 50000
#define NE 800000

typedef __attribute__((ext_vector_type(8))) short bf16x8;
typedef __attribute__((ext_vector_type(4))) float f32x4;

__device__ __forceinline__ short f2bf(float f) {
    union { float f; unsigned u; } v; v.f = f;
    return (short)((v.u + 0x7fffu + ((v.u >> 16) & 1u)) >> 16);
}

__device__ __forceinline__ float bf2f(short s) {
    union { unsigned u; float f; } v;
    v.u = ((unsigned)(unsigned short)s) << 16;
    return v.f;
}

__device__ __forceinline__ bf16x8 cvt8(const float* __restrict__ p) {
    const f32x4 a = *(const f32x4*)p;
    const f32x4 b = *(const f32x4*)(p + 4);
    bf16x8 r;
#pragma unroll
    for (int j = 0; j < 4; ++j) { r[j] = f2bf(a[j]); r[j + 4] = f2bf(b[j]); }
    return r;
}

// Stage W (KROWS x 128 row-major fp32) into LDS as swizzled bf16 MFMA B-fragments.
// If SIGMA: permute input rows k -> sigma(k) = (k&7)*16 + (k>>3) to match X-tilde packing.
template<int KROWS, int NTHREADS, bool SIGMA>
__device__ __forceinline__ void stage_w(const float* __restrict__ W, short* lds, int tid) {
    constexpr int NSLOT = (KROWS / 32) * 8 * 64;
#pragma unroll 1
    for (int slot = tid; slot < NSLOT; slot += NTHREADS) {
        const int f = slot >> 6, l = slot & 63;
        const int s = f >> 3, t = f & 7;
        const int k0 = 32 * s + ((l >> 4) << 3);
        const int n = 16 * t + (l & 15);
        bf16x8 v;
#pragma unroll
        for (int j = 0; j < 8; ++j) {
            int k = k0 + j;
            if (SIGMA) k = (k & 7) * 16 + (k >> 3);
            v[j] = f2bf(W[k * 128 + n]);
        }
        *(bf16x8*)(lds + slot * 8) = v;
    }
}

// ---------------- counting sort by dst ----------------

__global__ void hist_kernel(const int* __restrict__ eidx, int* __restrict__ cnt) {
    const int e = blockIdx.x * blockDim.x + threadIdx.x;
    if (e < NE) atomicAdd(&cnt[eidx[NE + e]], 1);
}

__global__ __launch_bounds__(1024) void scan1_kernel(const int* __restrict__ cnt,
                                                     int* __restrict__ part,
                                                     int* __restrict__ bsum) {
    __shared__ int s[1024];
    const int t = threadIdx.x;
    const int i = blockIdx.x * 1024 + t;
    const int v = (i < NN) ? cnt[i] : 0;
    int x = v;
    s[t] = x;
    __syncthreads();
    for (int off = 1; off < 1024; off <<= 1) {
        const int y = (t >= off) ? s[t - off] : 0;
        __syncthreads();
        x += y;
        s[t] = x;
        __syncthreads();
    }
    if (i < NN) part[i] = x - v;
    if (t == 1023) bsum[blockIdx.x] = x;
}

__global__ void scan2_kernel(const int* __restrict__ bsum, int* __restrict__ boff, int nb) {
    if (threadIdx.x == 0 && blockIdx.x == 0) {
        int acc = 0;
        for (int b = 0; b < nb; ++b) { boff[b] = acc; acc += bsum[b]; }
    }
}

__global__ __launch_bounds__(1024) void scan3_kernel(const int* __restrict__ part,
                                                     const int* __restrict__ boff,
                                                     int* __restrict__ cursor) {
    const int i = blockIdx.x * 1024 + threadIdx.x;
    if (i < NN) cursor[i] = part[i] + boff[i >> 10];
}

// scatter edge -> sorted position; also de-reference eidx so the hot kernel
// reads srs/dss as streams (no double indirection).
__global__ void scatter_kernel(const int* __restrict__ eidx, int* __restrict__ cursor,
                               int* __restrict__ perm, int* __restrict__ srs,
                               int* __restrict__ dss) {
    const int e = blockIdx.x * blockDim.x + threadIdx.x;
    if (e < NE) {
        const int d = eidx[NE + e];
        const int pos = atomicAdd(&cursor[d], 1);
        perm[pos] = e;
        srs[pos] = eidx[e];
        dss[pos] = d;
    }
}

// ---------------- P~ = h @ Wm1[0:128], Q~ = h @ Wm1[128:256] + bm1 ----------------
// sigma-swizzled bf16: element (node, t*16+col) stored at node*128 + col*8 + t.
__global__ __launch_bounds__(256) void node_pq_kernel(
    const float* __restrict__ h, const float* __restrict__ Wm1,
    const float* __restrict__ bm1,
    short* __restrict__ Pb, short* __restrict__ Qb)
{
    __shared__ short sWa[16384];
    __shared__ short sWb[16384];
    const int tid = threadIdx.x;
    stage_w<128, 256, false>(Wm1, sWa, tid);
    stage_w<128, 256, false>(Wm1 + 128 * 128, sWb, tid);
    __syncthreads();
    const int wave = tid >> 6, lane = tid & 63;
    const int q = lane >> 4, col = lane & 15;
    float b1v[8];
#pragma unroll
    for (int t = 0; t < 8; ++t) b1v[t] = bm1[t * 16 + col];
    for (int tile = blockIdx.x * 4 + wave; tile < NN / 16; tile += gridDim.x * 4) {
        const int r0 = tile * 16;
        f32x4 aP[8], aQ[8];
#pragma unroll
        for (int t = 0; t < 8; ++t) {
            aP[t] = {0.f, 0.f, 0.f, 0.f};
            const float b = b1v[t];
            aQ[t] = {b, b, b, b};  // fold bm1 into Q~
        }
#pragma unroll
        for (int s = 0; s < 4; ++s) {
            const bf16x8 ah = cvt8(&h[(r0 + col) * 128 + s * 32 + q * 8]);
#pragma unroll
            for (int t = 0; t < 8; ++t) {
                const bf16x8 ba = *(const bf16x8*)(sWa + ((s * 8 + t) * 64 + lane) * 8);
                const bf16x8 bb = *(const bf16x8*)(sWb + ((s * 8 + t) * 64 + lane) * 8);
                aP[t] = __builtin_amdgcn_mfma_f32_16x16x32_bf16(ah, ba, aP[t], 0, 0, 0);
                aQ[t] = __builtin_amdgcn_mfma_f32_16x16x32_bf16(ah, bb, aQ[t], 0, 0, 0);
            }
        }
#pragma unroll
        for (int r = 0; r < 4; ++r) {
            const size_t row = (size_t)(r0 + q * 4 + r) * 128;
            bf16x8 vp, vq;
#pragma unroll
            for (int t = 0; t < 8; ++t) { vp[t] = f2bf(aP[t][r]); vq[t] = f2bf(aQ[t][r]); }
            *(bf16x8*)(Pb + row + col * 8) = vp;
            *(bf16x8*)(Qb + row + col * 8) = vq;
        }
    }
}

// ---------------- edge kernel over dst-sorted tiles ----------------
// acc1 = P~[src] + Q~[dst](+b1) + ea@W1c ; X = relu ; msg = relu(X@Wm2+b2);
// segmented reduce over sorted dst runs; one atomic per run-head.
__global__ __launch_bounds__(512) void edge_kernel(
    const short* __restrict__ Pb, const short* __restrict__ Qb,
    const float* __restrict__ ea, const float* __restrict__ W1c,
    const float* __restrict__ Wm2, const float* __restrict__ bm2,
    const int* __restrict__ srs, const int* __restrict__ dss,
    const int* __restrict__ perm, float* __restrict__ agg)
{
    __shared__ short sW2[16384];
    __shared__ short sW1c[4096];
    __shared__ short sX[8][16 * 136];
    const int tid = threadIdx.x;
    const int wave = tid >> 6, lane = tid & 63;
    const int q = lane >> 4, col = lane & 15;
    float b2v[8];
#pragma unroll
    for (int t = 0; t < 8; ++t) b2v[t] = bm2[t * 16 + col];
    stage_w<128, 512, true>(Wm2, sW2, tid);
    stage_w<32, 512, false>(W1c, sW1c, tid);
    __syncthreads();
    short* myX = &sX[wave][0];
    for (int tile = blockIdx.x * 8 + wave; tile < NE / 16; tile += gridDim.x * 8) {
        const int e0 = tile * 16;
        int sr[4], dr[4];
#pragma unroll
        for (int r = 0; r < 4; ++r) {
            sr[r] = srs[e0 + q * 4 + r];
            dr[r] = dss[e0 + q * 4 + r];
        }
        const int pe = perm[e0 + col];
        // --- run-structure mask (wave-uniform 16 bits; bit e: key[e]==key[e-1]) ---
        const int prev3 = __shfl_up(dr[3], 16);
        unsigned qm = 0;
        if (q > 0 && dr[0] == prev3) qm |= 1u;
        if (dr[1] == dr[0]) qm |= 2u;
        if (dr[2] == dr[1]) qm |= 4u;
        if (dr[3] == dr[2]) qm |= 8u;
        const unsigned o1 = (unsigned)__shfl_xor((int)qm, 16);
        const unsigned o2 = (unsigned)__shfl_xor((int)qm, 32);
        const unsigned o3 = (unsigned)__shfl_xor((int)o1, 32);
        const unsigned eqmask = (qm << (q * 4)) | (o1 << ((q ^ 1) * 4)) |
                                (o2 << ((q ^ 2) * 4)) | (o3 << ((q ^ 3) * 4));
        int head[4], qe[4];
#pragma unroll
        for (int r = 0; r < 4; ++r) {
            const int e = q * 4 + r;
            head[r] = !((eqmask >> e) & 1u);
            const unsigned after = ~(eqmask >> (e + 1));  // never 0
            const int run = __builtin_ctz(after);
            qe[r] = (e + run) >> 2;
        }
        // --- layer 1 ---
        f32x4 acc1[8];
#pragma unroll
        for (int r = 0; r < 4; ++r) {
            const bf16x8 vp = *(const bf16x8*)(Pb + (size_t)sr[r] * 128 + col * 8);
            const bf16x8 vq = *(const bf16x8*)(Qb + (size_t)dr[r] * 128 + col * 8);
#pragma unroll
            for (int t = 0; t < 8; ++t)
                acc1[t][r] = bf2f(vp[t]) + bf2f(vq[t]);
        }
        const bf16x8 aea = cvt8(&ea[(size_t)pe * 32 + q * 8]);
#pragma unroll
        for (int t = 0; t < 8; ++t) {
            const bf16x8 bw = *(const bf16x8*)(sW1c + (t * 64 + lane) * 8);
            acc1[t] = __builtin_amdgcn_mfma_f32_16x16x32_bf16(aea, bw, acc1[t], 0, 0, 0);
        }
#pragma unroll
        for (int r = 0; r < 4; ++r) {
            bf16x8 vx;
#pragma unroll
            for (int t = 0; t < 8; ++t) {
                const float x = acc1[t][r];
                vx[t] = f2bf(x > 0.f ? x : 0.f);
            }
            *(bf16x8*)(myX + (q * 4 + r) * 136 + col * 8) = vx;
        }
        // --- layer 2 ---
        f32x4 acc2[8];
#pragma unroll
        for (int t = 0; t < 8; ++t) {
            const float b = b2v[t];
            acc2[t] = {b, b, b, b};
        }
#pragma unroll
        for (int s = 0; s < 4; ++s) {
            const bf16x8 ax = *(const bf16x8*)(myX + col * 136 + s * 32 + q * 8);
#pragma unroll
            for (int t = 0; t < 8; ++t) {
                const bf16x8 bw = *(const bf16x8*)(sW2 + ((s * 8 + t) * 64 + lane) * 8);
                acc2[t] = __builtin_amdgcn_mfma_f32_16x16x32_bf16(ax, bw, acc2[t], 0, 0, 0);
            }
        }
        // --- segmented reduction over runs + per-head atomic ---
#pragma unroll
        for (int t = 0; t < 8; ++t) {
            float m0 = acc2[t][0]; m0 = m0 > 0.f ? m0 : 0.f;
            float m1 = acc2[t][1]; m1 = m1 > 0.f ? m1 : 0.f;
            float m2 = acc2[t][2]; m2 = m2 > 0.f ? m2 : 0.f;
            float m3 = acc2[t][3]; m3 = m3 > 0.f ? m3 : 0.f;
            const float s3 = m3;
            const float s2 = m2 + ((qm & 8u) ? s3 : 0.f);
            const float s1 = m1 + ((qm & 4u) ? s2 : 0.f);
            const float s0 = m0 + ((qm & 2u) ? s1 : 0.f);
            // quad-prefix-run sums of all 4 quads via butterfly
            const float p1 = __shfl_xor(s0, 16);
            const float p2 = __shfl_xor(s0, 32);
            const float p3 = __shfl_xor(p1, 32);
            const float seg[4] = {s0, s1, s2, s3};
#pragma unroll
            for (int r = 0; r < 4; ++r) {
                if (head[r]) {
                    float tot = seg[r];
#pragma unroll
                    for (int j = 1; j < 4; ++j) {
                        if (j > q && j <= qe[r]) {
                            const int jx = j ^ q;
                            tot += (jx == 1) ? p1 : (jx == 2) ? p2 : p3;
                        }
                    }
                    if (tot != 0.f)
                        unsafeAtomicAdd(&agg[(size_t)dr[r] * 128 + t * 16 + col], tot);
                }
            }
        }
    }
}

// ---------------- update MLP + residual ----------------

__global__ __launch_bounds__(512) void update_kernel(
    const float* __restrict__ h, const float* __restrict__ agg,
    const float* __restrict__ Wu1, const float* __restrict__ bu1,
    const float* __restrict__ Wu2, const float* __restrict__ bu2,
    float* __restrict__ out)
{
    __shared__ short sWa[16384];
    __shared__ short sWb[16384];
    __shared__ short sW2[16384];
    __shared__ short sX[8][16 * 136];
    const int tid = threadIdx.x;
    const int wave = tid >> 6, lane = tid & 63;
    const int q = lane >> 4, col = lane & 15;
    float b1v[8], b2v[8];
#pragma unroll
    for (int t = 0; t < 8; ++t) { b1v[t] = bu1[t * 16 + col]; b2v[t] = bu2[t * 16 + col]; }
    stage_w<128, 512, false>(Wu1, sWa, tid);
    stage_w<128, 512, false>(Wu1 + 128 * 128, sWb, tid);
    stage_w<128, 512, true>(Wu2, sW2, tid);
    __syncthreads();
    short* myX = &sX[wave][0];
    for (int tile = blockIdx.x * 8 + wave; tile < NN / 16; tile += gridDim.x * 8) {
        const int r0 = tile * 16;
        f32x4 acc1[8];
#pragma unroll
        for (int t = 0; t < 8; ++t) {
            const float b = b1v[t];
            acc1[t] = {b, b, b, b};
        }
#pragma unroll
        for (int s = 0; s < 4; ++s) {
            const bf16x8 ahh = cvt8(&h[(r0 + col) * 128 + s * 32 + q * 8]);
            const bf16x8 aag = cvt8(&agg[(r0 + col) * 128 + s * 32 + q * 8]);
#pragma unroll
            for (int t = 0; t < 8; ++t) {
                const bf16x8 ba = *(const bf16x8*)(sWa + ((s * 8 + t) * 64 + lane) * 8);
                const bf16x8 bb = *(const bf16x8*)(sWb + ((s * 8 + t) * 64 + lane) * 8);
                acc1[t] = __builtin_amdgcn_mfma_f32_16x16x32_bf16(ahh, ba, acc1[t], 0, 0, 0);
                acc1[t] = __builtin_amdgcn_mfma_f32_16x16x32_bf16(aag, bb, acc1[t], 0, 0, 0);
            }
        }
#pragma unroll
        for (int r = 0; r < 4; ++r) {
            bf16x8 vx;
#pragma unroll
            for (int t = 0; t < 8; ++t) {
                const float x = acc1[t][r];
                vx[t] = f2bf(x > 0.f ? x : 0.f);
            }
            *(bf16x8*)(myX + (q * 4 + r) * 136 + col * 8) = vx;
        }
        f32x4 acc2[8];
#pragma unroll
        for (int t = 0; t < 8; ++t) {
            const float b = b2v[t];
#pragma unroll
            for (int r = 0; r < 4; ++r)
                acc2[t][r] = b + h[(r0 + q * 4 + r) * 128 + t * 16 + col];
        }
#pragma unroll
        for (int s = 0; s < 4; ++s) {
            const bf16x8 ax = *(const bf16x8*)(myX + col * 136 + s * 32 + q * 8);
#pragma unroll
            for (int t = 0; t < 8; ++t) {
                const bf16x8 bw = *(const bf16x8*)(sW2 + ((s * 8 + t) * 64 + lane) * 8);
                acc2[t] = __builtin_amdgcn_mfma_f32_16x16x32_bf16(ax, bw, acc2[t], 0, 0, 0);
            }
        }
#pragma unroll
        for (int t = 0; t < 8; ++t)
#pragma unroll
            for (int r = 0; r < 4; ++r)
                out[(r0 + q * 4 + r) * 128 + t * 16 + col] = acc2[t][r];
    }
}

extern "C" void kernel_launch(void* const* d_in, const int* in_sizes, int n_in,
                              void* d_out, int out_size, void* d_ws, size_t ws_size,
                              hipStream_t stream) {
    const float* h   = (const float*)d_in[0];
    const float* ea  = (const float*)d_in[1];
    const float* Wm1 = (const float*)d_in[2];
    const float* bm1 = (const float*)d_in[3];
    const float* Wm2 = (const float*)d_in[4];
    const float* bm2 = (const float*)d_in[5];
    const float* Wu1 = (const float*)d_in[6];
    const float* bu1 = (const float*)d_in[7];
    const float* Wu2 = (const float*)d_in[8];
    const float* bu2 = (const float*)d_in[9];
    const int* eidx  = (const int*)d_in[10];
    float* out = (float*)d_out;

    short* Pb  = (short*)d_ws;                       // NN*128 bf16
    short* Qb  = Pb + (size_t)NN * 128;              // NN*128 bf16
    float* agg = (float*)(Qb + (size_t)NN * 128);    // NN*128 fp32
    int* cnt    = (int*)(agg + (size_t)NN * 128);    // NN
    int* part   = cnt + NN;                          // NN
    int* bsum   = part + NN;                         // 64
    int* boff   = bsum + 64;                         // 64
    int* cursor = boff + 64;                         // NN
    int* perm   = cursor + NN;                       // NE
    int* srs    = perm + NE;                         // NE
    int* dss    = srs + NE;                          // NE

    const int NB_SCAN = (NN + 1023) / 1024;  // 49
    const int NB_E = (NE + 255) / 256;       // 3125

    hipMemsetAsync(cnt, 0, (size_t)NN * sizeof(int), stream);
    hipMemsetAsync(agg, 0, (size_t)NN * 128 * sizeof(float), stream);
    node_pq_kernel<<<512, 256, 0, stream>>>(h, Wm1, bm1, Pb, Qb);
    hist_kernel<<<NB_E, 256, 0, stream>>>(eidx, cnt);
    scan1_kernel<<<NB_SCAN, 1024, 0, stream>>>(cnt, part, bsum);
    scan2_kernel<<<1, 64, 0, stream>>>(bsum, boff, NB_SCAN);
    scan3_kernel<<<NB_SCAN, 1024, 0, stream>>>(part, boff, cursor);
    scatter_kernel<<<NB_E, 256, 0, stream>>>(eidx, cursor, perm, srs, dss);
    edge_kernel<<<512, 512, 0, stream>>>(Pb, Qb, ea, Wm1 + 256 * 128, Wm2, bm2,
                                         srs, dss, perm, agg);
    update_kernel<<<256, 512, 0, stream>>>(h, agg, Wu1, bu1, Wu2, bu2, out);
}

// Round 5
// 636.679 us; speedup vs baseline: 1.4814x; 1.0210x over previous
//
#include <hip/hip_runtime.h>

#define NN 50000
#define NE 800000

typedef __attribute__((ext_vector_type(8))) short bf16x8;
typedef __attribute__((ext_vector_type(4))) float f32x4;

__device__ __forceinline__ short f2bf(float f) {
    union { float f; unsigned u; } v; v.f = f;
    return (short)((v.u + 0x7fffu + ((v.u >> 16) & 1u)) >> 16);
}

__device__ __forceinline__ float bf2f(short s) {
    union { unsigned u; float f; } v;
    v.u = ((unsigned)(unsigned short)s) << 16;
    return v.f;
}

__device__ __forceinline__ bf16x8 cvt8(const float* __restrict__ p) {
    const f32x4 a = *(const f32x4*)p;
    const f32x4 b = *(const f32x4*)(p + 4);
    bf16x8 r;
#pragma unroll
    for (int j = 0; j < 4; ++j) { r[j] = f2bf(a[j]); r[j + 4] = f2bf(b[j]); }
    return r;
}

// ---------------- weight pre-swizzle (global bf16 MFMA B-fragments) ----------------
// Segment slot map (each slot = 64 lanes x ... -> 8 shorts at gW + slot*8):
// [0,2048)   Wm1a   [2048,4096) Wm1b   [4096,4608) W1c (32 rows)
// [4608,6656) Wm2 sigma   [6656,8704) Wu1a   [8704,10752) Wu1b   [10752,12800) Wu2 sigma
#define GW_M1A 0
#define GW_M1B 16384
#define GW_1C  32768
#define GW_M2S 36864
#define GW_U1A 53248
#define GW_U1B 69632
#define GW_U2S 86016
#define GW_TOT 102400

__global__ __launch_bounds__(256) void preswz_kernel(
    const float* __restrict__ Wm1, const float* __restrict__ Wm2,
    const float* __restrict__ Wu1, const float* __restrict__ Wu2,
    short* __restrict__ gW)
{
    const int slot = blockIdx.x * 256 + threadIdx.x;
    if (slot >= 12800) return;
    const float* W; int local; bool sigma = false;
    if (slot < 2048)       { W = Wm1;             local = slot; }
    else if (slot < 4096)  { W = Wm1 + 128 * 128; local = slot - 2048; }
    else if (slot < 4608)  { W = Wm1 + 256 * 128; local = slot - 4096; }
    else if (slot < 6656)  { W = Wm2;             local = slot - 4608; sigma = true; }
    else if (slot < 8704)  { W = Wu1;             local = slot - 6656; }
    else if (slot < 10752) { W = Wu1 + 128 * 128; local = slot - 8704; }
    else                   { W = Wu2;             local = slot - 10752; sigma = true; }
    const int f = local >> 6, l = local & 63;
    const int s = f >> 3, t = f & 7;
    const int k0 = 32 * s + ((l >> 4) << 3);
    const int n = 16 * t + (l & 15);
    bf16x8 v;
#pragma unroll
    for (int j = 0; j < 8; ++j) {
        int k = k0 + j;
        if (sigma) k = (k & 7) * 16 + (k >> 3);
        v[j] = f2bf(W[k * 128 + n]);
    }
    *(bf16x8*)(gW + (size_t)slot * 8) = v;
}

// LDS <- global pre-swizzled fragments, pure vector copy.
template<int NSLOT, int NTHREADS>
__device__ __forceinline__ void stage_copy(const short* __restrict__ g, short* lds, int tid) {
#pragma unroll
    for (int i = 0; i < NSLOT / NTHREADS; ++i) {
        const int s = tid + i * NTHREADS;
        *(bf16x8*)(lds + (size_t)s * 8) = *(const bf16x8*)(g + (size_t)s * 8);
    }
}

// ---------------- counting sort by dst ----------------

__global__ void hist_kernel(const int* __restrict__ eidx, int* __restrict__ cnt) {
    const int e = blockIdx.x * blockDim.x + threadIdx.x;
    if (e < NE) atomicAdd(&cnt[eidx[NE + e]], 1);
}

__global__ __launch_bounds__(1024) void scan1_kernel(const int* __restrict__ cnt,
                                                     int* __restrict__ part,
                                                     int* __restrict__ bsum) {
    __shared__ int s[1024];
    const int t = threadIdx.x;
    const int i = blockIdx.x * 1024 + t;
    const int v = (i < NN) ? cnt[i] : 0;
    int x = v;
    s[t] = x;
    __syncthreads();
    for (int off = 1; off < 1024; off <<= 1) {
        const int y = (t >= off) ? s[t - off] : 0;
        __syncthreads();
        x += y;
        s[t] = x;
        __syncthreads();
    }
    if (i < NN) part[i] = x - v;
    if (t == 1023) bsum[blockIdx.x] = x;
}

__global__ void scan2_kernel(const int* __restrict__ bsum, int* __restrict__ boff, int nb) {
    if (threadIdx.x == 0 && blockIdx.x == 0) {
        int acc = 0;
        for (int b = 0; b < nb; ++b) { boff[b] = acc; acc += bsum[b]; }
    }
}

__global__ __launch_bounds__(1024) void scan3_kernel(const int* __restrict__ part,
                                                     const int* __restrict__ boff,
                                                     int* __restrict__ cursor) {
    const int i = blockIdx.x * 1024 + threadIdx.x;
    if (i < NN) cursor[i] = part[i] + boff[i >> 10];
}

__global__ void scatter_kernel(const int* __restrict__ eidx, int* __restrict__ cursor,
                               int* __restrict__ perm, int2* __restrict__ sd2) {
    const int e = blockIdx.x * blockDim.x + threadIdx.x;
    if (e < NE) {
        const int d = eidx[NE + e];
        const int pos = atomicAdd(&cursor[d], 1);
        perm[pos] = e;
        sd2[pos] = make_int2(eidx[e], d);
    }
}

// ---------------- P~ = h @ Wm1[0:128], Q~ = h @ Wm1[128:256] + bm1 (sigma-swizzled bf16) ----------------

__global__ __launch_bounds__(256) void node_pq_kernel(
    const float* __restrict__ h, const short* __restrict__ gW,
    const float* __restrict__ bm1,
    short* __restrict__ Pb, short* __restrict__ Qb)
{
    __shared__ short sWa[16384];
    __shared__ short sWb[16384];
    const int tid = threadIdx.x;
    stage_copy<2048, 256>(gW + GW_M1A, sWa, tid);
    stage_copy<2048, 256>(gW + GW_M1B, sWb, tid);
    __syncthreads();
    const int wave = tid >> 6, lane = tid & 63;
    const int q = lane >> 4, col = lane & 15;
    float b1v[8];
#pragma unroll
    for (int t = 0; t < 8; ++t) b1v[t] = bm1[t * 16 + col];
    for (int tile = blockIdx.x * 4 + wave; tile < NN / 16; tile += gridDim.x * 4) {
        const int r0 = tile * 16;
        f32x4 aP[8], aQ[8];
#pragma unroll
        for (int t = 0; t < 8; ++t) {
            aP[t] = {0.f, 0.f, 0.f, 0.f};
            const float b = b1v[t];
            aQ[t] = {b, b, b, b};
        }
#pragma unroll
        for (int s = 0; s < 4; ++s) {
            const bf16x8 ah = cvt8(&h[(r0 + col) * 128 + s * 32 + q * 8]);
#pragma unroll
            for (int t = 0; t < 8; ++t) {
                const bf16x8 ba = *(const bf16x8*)(sWa + ((s * 8 + t) * 64 + lane) * 8);
                const bf16x8 bb = *(const bf16x8*)(sWb + ((s * 8 + t) * 64 + lane) * 8);
                aP[t] = __builtin_amdgcn_mfma_f32_16x16x32_bf16(ah, ba, aP[t], 0, 0, 0);
                aQ[t] = __builtin_amdgcn_mfma_f32_16x16x32_bf16(ah, bb, aQ[t], 0, 0, 0);
            }
        }
#pragma unroll
        for (int r = 0; r < 4; ++r) {
            const size_t row = (size_t)(r0 + q * 4 + r) * 128;
            bf16x8 vp, vq;
#pragma unroll
            for (int t = 0; t < 8; ++t) { vp[t] = f2bf(aP[t][r]); vq[t] = f2bf(aQ[t][r]); }
            *(bf16x8*)(Pb + row + col * 8) = vp;
            *(bf16x8*)(Qb + row + col * 8) = vq;
        }
    }
}

// ---------------- edge kernel: dst-sorted tiles, 2-deep software pipeline ----------------

__global__ __launch_bounds__(512) void edge_kernel(
    const short* __restrict__ Pb, const short* __restrict__ Qb,
    const float* __restrict__ ea, const short* __restrict__ gW,
    const float* __restrict__ bm2,
    const int2* __restrict__ sd2, const int* __restrict__ perm,
    float* __restrict__ agg)
{
    __shared__ short sW2[16384];
    __shared__ short sW1c[4096];
    __shared__ short sX[8][16 * 136];
    const int tid = threadIdx.x;
    const int wave = tid >> 6, lane = tid & 63;
    const int q = lane >> 4, col = lane & 15;
    float b2v[8];
#pragma unroll
    for (int t = 0; t < 8; ++t) b2v[t] = bm2[t * 16 + col];
    stage_copy<2048, 512>(gW + GW_M2S, sW2, tid);
    stage_copy<512, 512>(gW + GW_1C, sW1c, tid);
    __syncthreads();
    short* myX = &sX[wave][0];
    const int T = NE / 16;
    const int GWV = gridDim.x * 8;
    int tile = blockIdx.x * 8 + wave;
    if (tile >= T) return;

    // prologue: indices, gathers, ea for first tile
    int2 sd[4];
#pragma unroll
    for (int r = 0; r < 4; ++r) sd[r] = sd2[tile * 16 + q * 4 + r];
    int pe = perm[tile * 16 + col];
    bf16x8 vp[4], vq[4];
#pragma unroll
    for (int r = 0; r < 4; ++r) {
        vp[r] = *(const bf16x8*)(Pb + (size_t)sd[r].x * 128 + col * 8);
        vq[r] = *(const bf16x8*)(Qb + (size_t)sd[r].y * 128 + col * 8);
    }
    f32x4 elo = *(const f32x4*)(ea + (size_t)pe * 32 + q * 8);
    f32x4 ehi = *(const f32x4*)(ea + (size_t)pe * 32 + q * 8 + 4);

    while (true) {
        // ---- A0: run-structure masks (consumes sd) ----
        int drs[4];
#pragma unroll
        for (int r = 0; r < 4; ++r) drs[r] = sd[r].y;
        const int prev3 = __shfl_up(drs[3], 16);
        unsigned qm = 0;
        if (q > 0 && drs[0] == prev3) qm |= 1u;
        if (drs[1] == drs[0]) qm |= 2u;
        if (drs[2] == drs[1]) qm |= 4u;
        if (drs[3] == drs[2]) qm |= 8u;
        const unsigned o1 = (unsigned)__shfl_xor((int)qm, 16);
        const unsigned o2 = (unsigned)__shfl_xor((int)qm, 32);
        const unsigned o3 = (unsigned)__shfl_xor((int)o1, 32);
        const unsigned eqmask = (qm << (q * 4)) | (o1 << ((q ^ 1) * 4)) |
                                (o2 << ((q ^ 2) * 4)) | (o3 << ((q ^ 3) * 4));

        // ---- issue next-tile index loads (sd regs free now) ----
        const int nt = tile + GWV;
        const bool has = nt < T;
        const int ntc = has ? nt : tile;
#pragma unroll
        for (int r = 0; r < 4; ++r) sd[r] = sd2[ntc * 16 + q * 4 + r];
        pe = perm[ntc * 16 + col];

        // ---- A1: layer-1 accumulator (consumes vp/vq/elo/ehi) ----
        f32x4 acc1[8];
#pragma unroll
        for (int r = 0; r < 4; ++r)
#pragma unroll
            for (int t = 0; t < 8; ++t)
                acc1[t][r] = bf2f(vp[r][t]) + bf2f(vq[r][t]);
        bf16x8 aea;
#pragma unroll
        for (int j = 0; j < 4; ++j) { aea[j] = f2bf(elo[j]); aea[4 + j] = f2bf(ehi[j]); }
#pragma unroll
        for (int t = 0; t < 8; ++t) {
            const bf16x8 bw = *(const bf16x8*)(sW1c + (t * 64 + lane) * 8);
            acc1[t] = __builtin_amdgcn_mfma_f32_16x16x32_bf16(aea, bw, acc1[t], 0, 0, 0);
        }

        // ---- issue next-tile gathers (vp/vq/elo/ehi regs free now) ----
#pragma unroll
        for (int r = 0; r < 4; ++r) {
            vp[r] = *(const bf16x8*)(Pb + (size_t)sd[r].x * 128 + col * 8);
            vq[r] = *(const bf16x8*)(Qb + (size_t)sd[r].y * 128 + col * 8);
        }
        elo = *(const f32x4*)(ea + (size_t)pe * 32 + q * 8);
        ehi = *(const f32x4*)(ea + (size_t)pe * 32 + q * 8 + 4);

        // ---- B: X round-trip + layer 2 + segmented reduce + atomics ----
#pragma unroll
        for (int r = 0; r < 4; ++r) {
            bf16x8 vx;
#pragma unroll
            for (int t = 0; t < 8; ++t) {
                const float x = acc1[t][r];
                vx[t] = f2bf(x > 0.f ? x : 0.f);
            }
            *(bf16x8*)(myX + (q * 4 + r) * 136 + col * 8) = vx;
        }
        f32x4 acc2[8];
#pragma unroll
        for (int t = 0; t < 8; ++t) {
            const float b = b2v[t];
            acc2[t] = {b, b, b, b};
        }
#pragma unroll
        for (int s = 0; s < 4; ++s) {
            const bf16x8 ax = *(const bf16x8*)(myX + col * 136 + s * 32 + q * 8);
#pragma unroll
            for (int t = 0; t < 8; ++t) {
                const bf16x8 bw = *(const bf16x8*)(sW2 + ((s * 8 + t) * 64 + lane) * 8);
                acc2[t] = __builtin_amdgcn_mfma_f32_16x16x32_bf16(ax, bw, acc2[t], 0, 0, 0);
            }
        }
        if (eqmask == 0xFFFEu) {
            // fast path: whole tile is one dst run
#pragma unroll
            for (int t = 0; t < 8; ++t) {
                float m0 = acc2[t][0]; m0 = m0 > 0.f ? m0 : 0.f;
                float m1 = acc2[t][1]; m1 = m1 > 0.f ? m1 : 0.f;
                float m2 = acc2[t][2]; m2 = m2 > 0.f ? m2 : 0.f;
                float m3 = acc2[t][3]; m3 = m3 > 0.f ? m3 : 0.f;
                float s = (m0 + m1) + (m2 + m3);
                s += __shfl_xor(s, 16);
                s += __shfl_xor(s, 32);
                if (q == 0 && s != 0.f)
                    unsafeAtomicAdd(&agg[(size_t)drs[0] * 128 + t * 16 + col], s);
            }
        } else {
            int head[4], qe[4];
#pragma unroll
            for (int r = 0; r < 4; ++r) {
                const int e = q * 4 + r;
                head[r] = !((eqmask >> e) & 1u);
                const unsigned after = ~(eqmask >> (e + 1));
                const int run = __builtin_ctz(after);
                qe[r] = (e + run) >> 2;
            }
#pragma unroll
            for (int t = 0; t < 8; ++t) {
                float m0 = acc2[t][0]; m0 = m0 > 0.f ? m0 : 0.f;
                float m1 = acc2[t][1]; m1 = m1 > 0.f ? m1 : 0.f;
                float m2 = acc2[t][2]; m2 = m2 > 0.f ? m2 : 0.f;
                float m3 = acc2[t][3]; m3 = m3 > 0.f ? m3 : 0.f;
                const float s3 = m3;
                const float s2 = m2 + ((qm & 8u) ? s3 : 0.f);
                const float s1 = m1 + ((qm & 4u) ? s2 : 0.f);
                const float s0 = m0 + ((qm & 2u) ? s1 : 0.f);
                const float p1 = __shfl_xor(s0, 16);
                const float p2 = __shfl_xor(s0, 32);
                const float p3 = __shfl_xor(p1, 32);
                const float seg[4] = {s0, s1, s2, s3};
#pragma unroll
                for (int r = 0; r < 4; ++r) {
                    if (head[r]) {
                        float tot = seg[r];
#pragma unroll
                        for (int j = 1; j < 4; ++j) {
                            if (j > q && j <= qe[r]) {
                                const int jx = j ^ q;
                                tot += (jx == 1) ? p1 : (jx == 2) ? p2 : p3;
                            }
                        }
                        if (tot != 0.f)
                            unsafeAtomicAdd(&agg[(size_t)drs[r] * 128 + t * 16 + col], tot);
                    }
                }
            }
        }
        if (!has) break;
        tile = nt;
    }
}

// ---------------- update MLP + residual ----------------

__global__ __launch_bounds__(512) void update_kernel(
    const float* __restrict__ h, const float* __restrict__ agg,
    const short* __restrict__ gW, const float* __restrict__ bu1,
    const float* __restrict__ bu2, float* __restrict__ out)
{
    __shared__ short sWa[16384];
    __shared__ short sWb[16384];
    __shared__ short sW2[16384];
    __shared__ short sX[8][16 * 136];
    const int tid = threadIdx.x;
    const int wave = tid >> 6, lane = tid & 63;
    const int q = lane >> 4, col = lane & 15;
    float b1v[8], b2v[8];
#pragma unroll
    for (int t = 0; t < 8; ++t) { b1v[t] = bu1[t * 16 + col]; b2v[t] = bu2[t * 16 + col]; }
    stage_copy<2048, 512>(gW + GW_U1A, sWa, tid);
    stage_copy<2048, 512>(gW + GW_U1B, sWb, tid);
    stage_copy<2048, 512>(gW + GW_U2S, sW2, tid);
    __syncthreads();
    short* myX = &sX[wave][0];
    for (int tile = blockIdx.x * 8 + wave; tile < NN / 16; tile += gridDim.x * 8) {
        const int r0 = tile * 16;
        f32x4 acc1[8];
#pragma unroll
        for (int t = 0; t < 8; ++t) {
            const float b = b1v[t];
            acc1[t] = {b, b, b, b};
        }
#pragma unroll
        for (int s = 0; s < 4; ++s) {
            const bf16x8 ahh = cvt8(&h[(r0 + col) * 128 + s * 32 + q * 8]);
            const bf16x8 aag = cvt8(&agg[(r0 + col) * 128 + s * 32 + q * 8]);
#pragma unroll
            for (int t = 0; t < 8; ++t) {
                const bf16x8 ba = *(const bf16x8*)(sWa + ((s * 8 + t) * 64 + lane) * 8);
                const bf16x8 bb = *(const bf16x8*)(sWb + ((s * 8 + t) * 64 + lane) * 8);
                acc1[t] = __builtin_amdgcn_mfma_f32_16x16x32_bf16(ahh, ba, acc1[t], 0, 0, 0);
                acc1[t] = __builtin_amdgcn_mfma_f32_16x16x32_bf16(aag, bb, acc1[t], 0, 0, 0);
            }
        }
#pragma unroll
        for (int r = 0; r < 4; ++r) {
            bf16x8 vx;
#pragma unroll
            for (int t = 0; t < 8; ++t) {
                const float x = acc1[t][r];
                vx[t] = f2bf(x > 0.f ? x : 0.f);
            }
            *(bf16x8*)(myX + (q * 4 + r) * 136 + col * 8) = vx;
        }
        f32x4 acc2[8];
#pragma unroll
        for (int t = 0; t < 8; ++t) {
            const float b = b2v[t];
#pragma unroll
            for (int r = 0; r < 4; ++r)
                acc2[t][r] = b + h[(r0 + q * 4 + r) * 128 + t * 16 + col];
        }
#pragma unroll
        for (int s = 0; s < 4; ++s) {
            const bf16x8 ax = *(const bf16x8*)(myX + col * 136 + s * 32 + q * 8);
#pragma unroll
            for (int t = 0; t < 8; ++t) {
                const bf16x8 bw = *(const bf16x8*)(sW2 + ((s * 8 + t) * 64 + lane) * 8);
                acc2[t] = __builtin_amdgcn_mfma_f32_16x16x32_bf16(ax, bw, acc2[t], 0, 0, 0);
            }
        }
#pragma unroll
        for (int t = 0; t < 8; ++t)
#pragma unroll
            for (int r = 0; r < 4; ++r)
                out[(r0 + q * 4 + r) * 128 + t * 16 + col] = acc2[t][r];
    }
}

extern "C" void kernel_launch(void* const* d_in, const int* in_sizes, int n_in,
                              void* d_out, int out_size, void* d_ws, size_t ws_size,
                              hipStream_t stream) {
    const float* h   = (const float*)d_in[0];
    const float* ea  = (const float*)d_in[1];
    const float* Wm1 = (const float*)d_in[2];
    const float* bm1 = (const float*)d_in[3];
    const float* Wm2 = (const float*)d_in[4];
    const float* bm2 = (const float*)d_in[5];
    const float* Wu1 = (const float*)d_in[6];
    const float* bu1 = (const float*)d_in[7];
    const float* Wu2 = (const float*)d_in[8];
    const float* bu2 = (const float*)d_in[9];
    const int* eidx  = (const int*)d_in[10];
    float* out = (float*)d_out;

    short* gW  = (short*)d_ws;                       // 102400 shorts
    short* Pb  = gW + GW_TOT;                        // NN*128 bf16
    short* Qb  = Pb + (size_t)NN * 128;              // NN*128 bf16
    float* agg = (float*)(Qb + (size_t)NN * 128);    // NN*128 fp32
    int* cnt    = (int*)(agg + (size_t)NN * 128);    // NN
    int* part   = cnt + NN;                          // NN
    int* bsum   = part + NN;                         // 64
    int* boff   = bsum + 64;                         // 64
    int* cursor = boff + 64;                         // NN
    int2* sd2   = (int2*)(cursor + NN);              // NE int2 (8-B aligned)
    int* perm   = (int*)(sd2 + NE);                  // NE

    const int NB_SCAN = (NN + 1023) / 1024;  // 49
    const int NB_E = (NE + 255) / 256;       // 3125

    hipMemsetAsync(cnt, 0, (size_t)NN * sizeof(int), stream);
    hipMemsetAsync(agg, 0, (size_t)NN * 128 * sizeof(float), stream);
    preswz_kernel<<<50, 256, 0, stream>>>(Wm1, Wm2, Wu1, Wu2, gW);
    node_pq_kernel<<<512, 256, 0, stream>>>(h, gW, bm1, Pb, Qb);
    hist_kernel<<<NB_E, 256, 0, stream>>>(eidx, cnt);
    scan1_kernel<<<NB_SCAN, 1024, 0, stream>>>(cnt, part, bsum);
    scan2_kernel<<<1, 64, 0, stream>>>(bsum, boff, NB_SCAN);
    scan3_kernel<<<NB_SCAN, 1024, 0, stream>>>(part, boff, cursor);
    scatter_kernel<<<NB_E, 256, 0, stream>>>(eidx, cursor, perm, sd2);
    edge_kernel<<<512, 512, 0, stream>>>(Pb, Qb, ea, gW, bm2, sd2, perm, agg);
    update_kernel<<<256, 512, 0, stream>>>(h, agg, gW, bu1, bu2, out);
}

// Round 6
// 623.714 us; speedup vs baseline: 1.5122x; 1.0208x over previous
//
#include <hip/hip_runtime.h>

#define NN 50000
#define NE 800000

typedef __attribute__((ext_vector_type(8))) short bf16x8;
typedef __attribute__((ext_vector_type(4))) float f32x4;

__device__ __forceinline__ short f2bf(float f) {
    union { float f; unsigned u; } v; v.f = f;
    return (short)((v.u + 0x7fffu + ((v.u >> 16) & 1u)) >> 16);
}

__device__ __forceinline__ float bf2f(short s) {
    union { unsigned u; float f; } v;
    v.u = ((unsigned)(unsigned short)s) << 16;
    return v.f;
}

__device__ __forceinline__ bf16x8 cvt8(const float* __restrict__ p) {
    const f32x4 a = *(const f32x4*)p;
    const f32x4 b = *(const f32x4*)(p + 4);
    bf16x8 r;
#pragma unroll
    for (int j = 0; j < 4; ++j) { r[j] = f2bf(a[j]); r[j + 4] = f2bf(b[j]); }
    return r;
}

// gW slot map (slot = 8 shorts at gW + slot*8):
// [0,2048) Wm1a | [2048,4096) Wm1b | [4096,4608) W1c | [4608,6656) Wm2 sigma
// [6656,8704) Wu1a | [8704,10752) Wu1b | [10752,12800) Wu2 sigma
#define GW_M1A 0
#define GW_M1B 16384
#define GW_1C  32768
#define GW_M2S 36864
#define GW_U1A 53248
#define GW_U1B 69632
#define GW_U2S 86016
#define GW_TOT 102400

// Stage W (KROWS x 128 row-major fp32) -> LDS bf16 MFMA B-fragments (node_pq path).
template<int KROWS, int NTHREADS>
__device__ __forceinline__ void stage_w(const float* __restrict__ W, short* lds, int tid) {
    constexpr int NSLOT = (KROWS / 32) * 8 * 64;
#pragma unroll 1
    for (int slot = tid; slot < NSLOT; slot += NTHREADS) {
        const int f = slot >> 6, l = slot & 63;
        const int s = f >> 3, t = f & 7;
        const int k0 = 32 * s + ((l >> 4) << 3);
        const int n = 16 * t + (l & 15);
        bf16x8 v;
#pragma unroll
        for (int j = 0; j < 8; ++j) v[j] = f2bf(W[(k0 + j) * 128 + n]);
        *(bf16x8*)(lds + slot * 8) = v;
    }
}

template<int NSLOT, int NTHREADS>
__device__ __forceinline__ void stage_copy(const short* __restrict__ g, short* lds, int tid) {
#pragma unroll
    for (int i = 0; i < NSLOT / NTHREADS; ++i) {
        const int s = tid + i * NTHREADS;
        *(bf16x8*)(lds + (size_t)s * 8) = *(const bf16x8*)(g + (size_t)s * 8);
    }
}

// ---------------- mega kernel: node_pq (blocks 0..511) | preswz (512..561) | hist (562..) ----------------

__global__ __launch_bounds__(256) void mega_kernel(
    const float* __restrict__ h, const float* __restrict__ Wm1,
    const float* __restrict__ bm1, const float* __restrict__ Wm2,
    const float* __restrict__ Wu1, const float* __restrict__ Wu2,
    const int* __restrict__ eidx, short* __restrict__ gW,
    short* __restrict__ Pb, short* __restrict__ Qb, int* __restrict__ cnt)
{
    const int b = blockIdx.x;
    const int tid = threadIdx.x;
    if (b < 512) {
        // ---- node_pq: P~ = h@Wm1a (sigma bf16), Q~ = h@Wm1b + bm1 ----
        __shared__ short sWa[16384];
        __shared__ short sWb[16384];
        stage_w<128, 256>(Wm1, sWa, tid);
        stage_w<128, 256>(Wm1 + 128 * 128, sWb, tid);
        __syncthreads();
        const int wave = tid >> 6, lane = tid & 63;
        const int q = lane >> 4, col = lane & 15;
        float b1v[8];
#pragma unroll
        for (int t = 0; t < 8; ++t) b1v[t] = bm1[t * 16 + col];
        for (int tile = b * 4 + wave; tile < NN / 16; tile += 2048) {
            const int r0 = tile * 16;
            f32x4 aP[8], aQ[8];
#pragma unroll
            for (int t = 0; t < 8; ++t) {
                aP[t] = {0.f, 0.f, 0.f, 0.f};
                const float bb = b1v[t];
                aQ[t] = {bb, bb, bb, bb};
            }
#pragma unroll
            for (int s = 0; s < 4; ++s) {
                const bf16x8 ah = cvt8(&h[(r0 + col) * 128 + s * 32 + q * 8]);
#pragma unroll
                for (int t = 0; t < 8; ++t) {
                    const bf16x8 ba = *(const bf16x8*)(sWa + ((s * 8 + t) * 64 + lane) * 8);
                    const bf16x8 bb = *(const bf16x8*)(sWb + ((s * 8 + t) * 64 + lane) * 8);
                    aP[t] = __builtin_amdgcn_mfma_f32_16x16x32_bf16(ah, ba, aP[t], 0, 0, 0);
                    aQ[t] = __builtin_amdgcn_mfma_f32_16x16x32_bf16(ah, bb, aQ[t], 0, 0, 0);
                }
            }
#pragma unroll
            for (int r = 0; r < 4; ++r) {
                const size_t row = (size_t)(r0 + q * 4 + r) * 128;
                bf16x8 vp, vq;
#pragma unroll
                for (int t = 0; t < 8; ++t) { vp[t] = f2bf(aP[t][r]); vq[t] = f2bf(aQ[t][r]); }
                *(bf16x8*)(Pb + row + col * 8) = vp;
                *(bf16x8*)(Qb + row + col * 8) = vq;
            }
        }
    } else if (b < 562) {
        // ---- preswz: weights -> global bf16 fragments ----
        const int slot = (b - 512) * 256 + tid;
        if (slot < 12800) {
            const float* W; int local; bool sigma = false;
            if (slot < 2048)       { W = Wm1;             local = slot; }
            else if (slot < 4096)  { W = Wm1 + 128 * 128; local = slot - 2048; }
            else if (slot < 4608)  { W = Wm1 + 256 * 128; local = slot - 4096; }
            else if (slot < 6656)  { W = Wm2;             local = slot - 4608; sigma = true; }
            else if (slot < 8704)  { W = Wu1;             local = slot - 6656; }
            else if (slot < 10752) { W = Wu1 + 128 * 128; local = slot - 8704; }
            else                   { W = Wu2;             local = slot - 10752; sigma = true; }
            const int f = local >> 6, l = local & 63;
            const int s = f >> 3, t = f & 7;
            const int k0 = 32 * s + ((l >> 4) << 3);
            const int n = 16 * t + (l & 15);
            bf16x8 v;
#pragma unroll
            for (int j = 0; j < 8; ++j) {
                int k = k0 + j;
                if (sigma) k = (k & 7) * 16 + (k >> 3);
                v[j] = f2bf(W[k * 128 + n]);
            }
            *(bf16x8*)(gW + (size_t)slot * 8) = v;
        }
    } else {
        // ---- hist ----
        const int e = (b - 562) * 256 + tid;
        if (e < NE) atomicAdd(&cnt[eidx[NE + e]], 1);
    }
}

// ---------------- scan ----------------

__global__ __launch_bounds__(1024) void scan1_kernel(const int* __restrict__ cnt,
                                                     int* __restrict__ part,
                                                     int* __restrict__ bsum) {
    __shared__ int s[1024];
    const int t = threadIdx.x;
    const int i = blockIdx.x * 1024 + t;
    const int v = (i < NN) ? cnt[i] : 0;
    int x = v;
    s[t] = x;
    __syncthreads();
    for (int off = 1; off < 1024; off <<= 1) {
        const int y = (t >= off) ? s[t - off] : 0;
        __syncthreads();
        x += y;
        s[t] = x;
        __syncthreads();
    }
    if (i < NN) part[i] = x - v;
    if (t == 1023) bsum[blockIdx.x] = x;
}

__global__ __launch_bounds__(1024) void scan23_kernel(const int* __restrict__ part,
                                                      const int* __restrict__ bsum,
                                                      int* __restrict__ cursor) {
    __shared__ int off;
    if (threadIdx.x == 0) {
        int a = 0;
        for (int bb = 0; bb < (int)blockIdx.x; ++bb) a += bsum[bb];
        off = a;
    }
    __syncthreads();
    const int i = blockIdx.x * 1024 + threadIdx.x;
    if (i < NN) cursor[i] = part[i] + off;
}

// ---------------- scatter: perm edges to sorted order; also permute+cvt ea -> eb (bf16) ----------------

__global__ void scatter_kernel(const int* __restrict__ eidx, int* __restrict__ cursor,
                               const float* __restrict__ ea,
                               int2* __restrict__ sd2, short* __restrict__ eb) {
    const int e = blockIdx.x * blockDim.x + threadIdx.x;
    if (e < NE) {
        const int d = eidx[NE + e];
        const int pos = atomicAdd(&cursor[d], 1);
        sd2[pos] = make_int2(eidx[e], d);
        const float* src = ea + (size_t)e * 32;
        short* dst = eb + (size_t)pos * 32;
#pragma unroll
        for (int j = 0; j < 4; ++j) {
            const f32x4 a = *(const f32x4*)(src + j * 8);
            const f32x4 bq = *(const f32x4*)(src + j * 8 + 4);
            bf16x8 v;
#pragma unroll
            for (int k = 0; k < 4; ++k) { v[k] = f2bf(a[k]); v[4 + k] = f2bf(bq[k]); }
            *(bf16x8*)(dst + j * 8) = v;
        }
    }
}

// ---------------- edge kernel: dst-sorted tiles, segmented reduce, no pipeline ----------------

__global__ __launch_bounds__(512) void edge_kernel(
    const short* __restrict__ Pb, const short* __restrict__ Qb,
    const short* __restrict__ eb, const short* __restrict__ gW,
    const float* __restrict__ bm2,
    const int2* __restrict__ sd2, float* __restrict__ agg)
{
    __shared__ short sW2[16384];
    __shared__ short sW1c[4096];
    __shared__ short sX[8][16 * 136];
    const int tid = threadIdx.x;
    const int wave = tid >> 6, lane = tid & 63;
    const int q = lane >> 4, col = lane & 15;
    float b2v[8];
#pragma unroll
    for (int t = 0; t < 8; ++t) b2v[t] = bm2[t * 16 + col];
    stage_copy<2048, 512>(gW + GW_M2S, sW2, tid);
    stage_copy<512, 512>(gW + GW_1C, sW1c, tid);
    __syncthreads();
    short* myX = &sX[wave][0];
    for (int tile = blockIdx.x * 8 + wave; tile < NE / 16; tile += gridDim.x * 8) {
        const int e0 = tile * 16;
        int2 sd[4];
#pragma unroll
        for (int r = 0; r < 4; ++r) sd[r] = sd2[e0 + q * 4 + r];
        // run-structure mask
        const int prev3 = __shfl_up(sd[3].y, 16);
        unsigned qm = 0;
        if (q > 0 && sd[0].y == prev3) qm |= 1u;
        if (sd[1].y == sd[0].y) qm |= 2u;
        if (sd[2].y == sd[1].y) qm |= 4u;
        if (sd[3].y == sd[2].y) qm |= 8u;
        const unsigned o1 = (unsigned)__shfl_xor((int)qm, 16);
        const unsigned o2 = (unsigned)__shfl_xor((int)qm, 32);
        const unsigned o3 = (unsigned)__shfl_xor((int)o1, 32);
        const unsigned eqmask = (qm << (q * 4)) | (o1 << ((q ^ 1) * 4)) |
                                (o2 << ((q ^ 2) * 4)) | (o3 << ((q ^ 3) * 4));
        // layer 1: gathered P~[src] + Q~[dst](+b1)
        f32x4 acc1[8];
#pragma unroll
        for (int r = 0; r < 4; ++r) {
            const bf16x8 vp = *(const bf16x8*)(Pb + (size_t)sd[r].x * 128 + col * 8);
            const bf16x8 vq = *(const bf16x8*)(Qb + (size_t)sd[r].y * 128 + col * 8);
#pragma unroll
            for (int t = 0; t < 8; ++t)
                acc1[t][r] = bf2f(vp[t]) + bf2f(vq[t]);
        }
        // + ea @ W1c  (eb is sorted bf16: streamed b128 load)
        const bf16x8 aea = *(const bf16x8*)(eb + (size_t)(e0 + col) * 32 + q * 8);
#pragma unroll
        for (int t = 0; t < 8; ++t) {
            const bf16x8 bw = *(const bf16x8*)(sW1c + (t * 64 + lane) * 8);
            acc1[t] = __builtin_amdgcn_mfma_f32_16x16x32_bf16(aea, bw, acc1[t], 0, 0, 0);
        }
        // relu -> bf16 -> X~ LDS
#pragma unroll
        for (int r = 0; r < 4; ++r) {
            bf16x8 vx;
#pragma unroll
            for (int t = 0; t < 8; ++t) {
                const float x = acc1[t][r];
                vx[t] = f2bf(x > 0.f ? x : 0.f);
            }
            *(bf16x8*)(myX + (q * 4 + r) * 136 + col * 8) = vx;
        }
        // layer 2
        f32x4 acc2[8];
#pragma unroll
        for (int t = 0; t < 8; ++t) {
            const float b = b2v[t];
            acc2[t] = {b, b, b, b};
        }
#pragma unroll
        for (int s = 0; s < 4; ++s) {
            const bf16x8 ax = *(const bf16x8*)(myX + col * 136 + s * 32 + q * 8);
#pragma unroll
            for (int t = 0; t < 8; ++t) {
                const bf16x8 bw = *(const bf16x8*)(sW2 + ((s * 8 + t) * 64 + lane) * 8);
                acc2[t] = __builtin_amdgcn_mfma_f32_16x16x32_bf16(ax, bw, acc2[t], 0, 0, 0);
            }
        }
        // segmented reduce + atomics
        if (eqmask == 0xFFFEu) {
#pragma unroll
            for (int t = 0; t < 8; ++t) {
                float m0 = acc2[t][0]; m0 = m0 > 0.f ? m0 : 0.f;
                float m1 = acc2[t][1]; m1 = m1 > 0.f ? m1 : 0.f;
                float m2 = acc2[t][2]; m2 = m2 > 0.f ? m2 : 0.f;
                float m3 = acc2[t][3]; m3 = m3 > 0.f ? m3 : 0.f;
                float s = (m0 + m1) + (m2 + m3);
                s += __shfl_xor(s, 16);
                s += __shfl_xor(s, 32);
                if (q == 0 && s != 0.f)
                    unsafeAtomicAdd(&agg[(size_t)sd[0].y * 128 + t * 16 + col], s);
            }
        } else {
            int head[4], qe[4];
#pragma unroll
            for (int r = 0; r < 4; ++r) {
                const int e = q * 4 + r;
                head[r] = !((eqmask >> e) & 1u);
                const unsigned after = ~(eqmask >> (e + 1));
                const int run = __builtin_ctz(after);
                qe[r] = (e + run) >> 2;
            }
#pragma unroll
            for (int t = 0; t < 8; ++t) {
                float m0 = acc2[t][0]; m0 = m0 > 0.f ? m0 : 0.f;
                float m1 = acc2[t][1]; m1 = m1 > 0.f ? m1 : 0.f;
                float m2 = acc2[t][2]; m2 = m2 > 0.f ? m2 : 0.f;
                float m3 = acc2[t][3]; m3 = m3 > 0.f ? m3 : 0.f;
                const float s3 = m3;
                const float s2 = m2 + ((qm & 8u) ? s3 : 0.f);
                const float s1 = m1 + ((qm & 4u) ? s2 : 0.f);
                const float s0 = m0 + ((qm & 2u) ? s1 : 0.f);
                const float p1 = __shfl_xor(s0, 16);
                const float p2 = __shfl_xor(s0, 32);
                const float p3 = __shfl_xor(p1, 32);
                const float seg[4] = {s0, s1, s2, s3};
#pragma unroll
                for (int r = 0; r < 4; ++r) {
                    if (head[r]) {
                        float tot = seg[r];
#pragma unroll
                        for (int j = 1; j < 4; ++j) {
                            if (j > q && j <= qe[r]) {
                                const int jx = j ^ q;
                                tot += (jx == 1) ? p1 : (jx == 2) ? p2 : p3;
                            }
                        }
                        if (tot != 0.f)
                            unsafeAtomicAdd(&agg[(size_t)sd[r].y * 128 + t * 16 + col], tot);
                    }
                }
            }
        }
    }
}

// ---------------- update MLP + residual ----------------

__global__ __launch_bounds__(512) void update_kernel(
    const float* __restrict__ h, const float* __restrict__ agg,
    const short* __restrict__ gW, const float* __restrict__ bu1,
    const float* __restrict__ bu2, float* __restrict__ out)
{
    __shared__ short sWa[16384];
    __shared__ short sWb[16384];
    __shared__ short sW2[16384];
    __shared__ short sX[8][16 * 136];
    const int tid = threadIdx.x;
    const int wave = tid >> 6, lane = tid & 63;
    const int q = lane >> 4, col = lane & 15;
    float b1v[8], b2v[8];
#pragma unroll
    for (int t = 0; t < 8; ++t) { b1v[t] = bu1[t * 16 + col]; b2v[t] = bu2[t * 16 + col]; }
    stage_copy<2048, 512>(gW + GW_U1A, sWa, tid);
    stage_copy<2048, 512>(gW + GW_U1B, sWb, tid);
    stage_copy<2048, 512>(gW + GW_U2S, sW2, tid);
    __syncthreads();
    short* myX = &sX[wave][0];
    for (int tile = blockIdx.x * 8 + wave; tile < NN / 16; tile += gridDim.x * 8) {
        const int r0 = tile * 16;
        f32x4 acc1[8];
#pragma unroll
        for (int t = 0; t < 8; ++t) {
            const float b = b1v[t];
            acc1[t] = {b, b, b, b};
        }
#pragma unroll
        for (int s = 0; s < 4; ++s) {
            const bf16x8 ahh = cvt8(&h[(r0 + col) * 128 + s * 32 + q * 8]);
            const bf16x8 aag = cvt8(&agg[(r0 + col) * 128 + s * 32 + q * 8]);
#pragma unroll
            for (int t = 0; t < 8; ++t) {
                const bf16x8 ba = *(const bf16x8*)(sWa + ((s * 8 + t) * 64 + lane) * 8);
                const bf16x8 bb = *(const bf16x8*)(sWb + ((s * 8 + t) * 64 + lane) * 8);
                acc1[t] = __builtin_amdgcn_mfma_f32_16x16x32_bf16(ahh, ba, acc1[t], 0, 0, 0);
                acc1[t] = __builtin_amdgcn_mfma_f32_16x16x32_bf16(aag, bb, acc1[t], 0, 0, 0);
            }
        }
#pragma unroll
        for (int r = 0; r < 4; ++r) {
            bf16x8 vx;
#pragma unroll
            for (int t = 0; t < 8; ++t) {
                const float x = acc1[t][r];
                vx[t] = f2bf(x > 0.f ? x : 0.f);
            }
            *(bf16x8*)(myX + (q * 4 + r) * 136 + col * 8) = vx;
        }
        f32x4 acc2[8];
#pragma unroll
        for (int t = 0; t < 8; ++t) {
            const float b = b2v[t];
#pragma unroll
            for (int r = 0; r < 4; ++r)
                acc2[t][r] = b + h[(r0 + q * 4 + r) * 128 + t * 16 + col];
        }
#pragma unroll
        for (int s = 0; s < 4; ++s) {
            const bf16x8 ax = *(const bf16x8*)(myX + col * 136 + s * 32 + q * 8);
#pragma unroll
            for (int t = 0; t < 8; ++t) {
                const bf16x8 bw = *(const bf16x8*)(sW2 + ((s * 8 + t) * 64 + lane) * 8);
                acc2[t] = __builtin_amdgcn_mfma_f32_16x16x32_bf16(ax, bw, acc2[t], 0, 0, 0);
            }
        }
#pragma unroll
        for (int t = 0; t < 8; ++t)
#pragma unroll
            for (int r = 0; r < 4; ++r)
                out[(r0 + q * 4 + r) * 128 + t * 16 + col] = acc2[t][r];
    }
}

extern "C" void kernel_launch(void* const* d_in, const int* in_sizes, int n_in,
                              void* d_out, int out_size, void* d_ws, size_t ws_size,
                              hipStream_t stream) {
    const float* h   = (const float*)d_in[0];
    const float* ea  = (const float*)d_in[1];
    const float* Wm1 = (const float*)d_in[2];
    const float* bm1 = (const float*)d_in[3];
    const float* Wm2 = (const float*)d_in[4];
    const float* bm2 = (const float*)d_in[5];
    const float* Wu1 = (const float*)d_in[6];
    const float* bu1 = (const float*)d_in[7];
    const float* Wu2 = (const float*)d_in[8];
    const float* bu2 = (const float*)d_in[9];
    const int* eidx  = (const int*)d_in[10];
    float* out = (float*)d_out;

    short* gW  = (short*)d_ws;                       // 102400 shorts
    short* Pb  = gW + GW_TOT;                        // NN*128 bf16
    short* Qb  = Pb + (size_t)NN * 128;              // NN*128 bf16
    float* agg = (float*)(Qb + (size_t)NN * 128);    // NN*128 fp32
    int* cnt    = (int*)(agg + (size_t)NN * 128);    // NN
    int* part   = cnt + NN;                          // NN
    int* bsum   = part + NN;                         // 64
    int* cursor = bsum + 64;                         // NN
    int2* sd2   = (int2*)(cursor + NN);              // NE int2
    short* eb   = (short*)(sd2 + NE);                // NE*32 bf16 (sorted edge attrs)

    const int NB_SCAN = (NN + 1023) / 1024;  // 49
    const int NB_E = (NE + 255) / 256;       // 3125

    hipMemsetAsync(cnt, 0, (size_t)NN * sizeof(int), stream);
    hipMemsetAsync(agg, 0, (size_t)NN * 128 * sizeof(float), stream);
    mega_kernel<<<512 + 50 + NB_E, 256, 0, stream>>>(h, Wm1, bm1, Wm2, Wu1, Wu2,
                                                     eidx, gW, Pb, Qb, cnt);
    scan1_kernel<<<NB_SCAN, 1024, 0, stream>>>(cnt, part, bsum);
    scan23_kernel<<<NB_SCAN, 1024, 0, stream>>>(part, bsum, cursor);
    scatter_kernel<<<NB_E, 256, 0, stream>>>(eidx, cursor, ea, sd2, eb);
    edge_kernel<<<512, 512, 0, stream>>>(Pb, Qb, eb, gW, bm2, sd2, agg);
    update_kernel<<<392, 512, 0, stream>>>(h, agg, gW, bu1, bu2, out);
}